// Round 9
// baseline (120.168 us; speedup 1.0000x reference)
//
#include <hip/hip_runtime.h>

// PINN beam residual: 1->16->16->2 tanh MLP with analytic 1st/2nd/3rd
// derivatives w.r.t. the scalar input. Outputs (u, w, wx, N, M, Q) concat.
//
// R1: hw tanh (exp2+rcp)  -> 50us, VALU 95%, but ~2.3x inst bloat.
// R2-R7: packed-fp32 dead end, two stacked causes finally identified:
//   (a) v_pk_fma_f32 is RATE-NEUTRAL on MI355X (fp32 peak 157 TF already
//       = 1 FMA/lane/cy; packed would imply 314). R2's "win" was issue
//       reduction only, pipe time identical.
//   (b) allocator never grants >64 arch VGPRs here; designs with >=64
//       mandatory-live values got AGPR-parked (v_accvgpr shuffles ~= the
//       persistent 2x instruction bloat, VGPR_Count 48-84 every round).
// R8: fit in 64 VGPRs BY DESIGN. Scalar v_fma_f32 with SGPR weight operand.
//   Layer-2 split into two j-passes of 8 units -> 32 live accumulators;
//   layer-1 tanh values (16 regs) kept across passes, jets rebuilt cheaply.
//   Prep-kernel packs {c,-2c^2,-2c^3,b1,b2,W3,b3,W2^T} into d_ws; main
//   kernel reads it with wave-uniform addresses -> s_load to SGPRs.
//   No LDS, no arrays, no pk. ~1760 inst/thread hand count.

constexpr float EA_CONST = 1000.0f;
constexpr float EI_CONST = 100.0f;
constexpr float TWO_LOG2E = 2.8853900817779268f;

__device__ __forceinline__ float fast_tanh(float x) {
    float e = __builtin_amdgcn_exp2f(x * TWO_LOG2E);
    float r = __builtin_amdgcn_rcpf(1.0f + e);
    return fmaf(-2.0f, r, 1.0f);
}

// const-block layout (floats): 0:c[16] 16:k2[16] 32:k3[16] 48:b1[16]
// 64:b2[16] 80:W3r0[16] 96:W3r1[16] 112:b3[2] 128:W2t[256] (i*16+j)
__global__ __launch_bounds__(256) void pinn_prep(
    const float* __restrict__ W1, const float* __restrict__ b1,
    const float* __restrict__ W2, const float* __restrict__ b2,
    const float* __restrict__ W3, const float* __restrict__ b3,
    float* __restrict__ cb)
{
    int t = threadIdx.x;
    if (t < 16) {
        float c = W1[t] * 0.5f;              // W1_i / L, L = 2
        cb[t]      = c;
        cb[16 + t] = -2.0f * c * c;
        cb[32 + t] = -2.0f * c * c * c;
        cb[48 + t] = b1[t];
        cb[64 + t] = b2[t];
    }
    if (t < 32) cb[80 + t] = W3[t];
    if (t < 2)  cb[112 + t] = b3[t];
    cb[128 + (t & 15) * 16 + (t >> 4)] = W2[t];   // W2t[i][j] = W2[j][i]
}

#define CC(i)    cb[i]
#define K2(i)    cb[16 + (i)]
#define K3(i)    cb[32 + (i)]
#define B1(i)    cb[48 + (i)]
#define B2(j)    cb[64 + (j)]
#define W30(j)   cb[80 + (j)]
#define W31(j)   cb[96 + (j)]
#define W2T(i,j) cb[128 + (i) * 16 + (j)]

__global__ __launch_bounds__(256) void pinn_main(
    const float* __restrict__ x, const float* __restrict__ cb,
    float* __restrict__ out, int n)
{
    int idx = blockIdx.x * blockDim.x + threadIdx.x;
    if (idx >= n) return;
    float xr = x[idx];

    float T0, T1, T2, T3, T4, T5, T6, T7,
          T8, T9, T10, T11, T12, T13, T14, T15;

    float u = 0.0f, w = 0.0f, up = 0.0f, wp = 0.0f, wpp = 0.0f, wppp = 0.0f;

    // 4 fma into the 8 j-accumulator quads for one layer-1 unit i
#define ACC8(i, a0, a1v, a2v, a3v, JB)                                      \
    Z0 = fmaf(W2T(i, JB + 0), a0, Z0);  P0 = fmaf(W2T(i, JB + 0), a1v, P0); \
    Q0 = fmaf(W2T(i, JB + 0), a2v, Q0); R0 = fmaf(W2T(i, JB + 0), a3v, R0); \
    Z1 = fmaf(W2T(i, JB + 1), a0, Z1);  P1 = fmaf(W2T(i, JB + 1), a1v, P1); \
    Q1 = fmaf(W2T(i, JB + 1), a2v, Q1); R1 = fmaf(W2T(i, JB + 1), a3v, R1); \
    Z2 = fmaf(W2T(i, JB + 2), a0, Z2);  P2 = fmaf(W2T(i, JB + 2), a1v, P2); \
    Q2 = fmaf(W2T(i, JB + 2), a2v, Q2); R2 = fmaf(W2T(i, JB + 2), a3v, R2); \
    Z3 = fmaf(W2T(i, JB + 3), a0, Z3);  P3 = fmaf(W2T(i, JB + 3), a1v, P3); \
    Q3 = fmaf(W2T(i, JB + 3), a2v, Q3); R3 = fmaf(W2T(i, JB + 3), a3v, R3); \
    Z4 = fmaf(W2T(i, JB + 4), a0, Z4);  P4 = fmaf(W2T(i, JB + 4), a1v, P4); \
    Q4 = fmaf(W2T(i, JB + 4), a2v, Q4); R4 = fmaf(W2T(i, JB + 4), a3v, R4); \
    Z5 = fmaf(W2T(i, JB + 5), a0, Z5);  P5 = fmaf(W2T(i, JB + 5), a1v, P5); \
    Q5 = fmaf(W2T(i, JB + 5), a2v, Q5); R5 = fmaf(W2T(i, JB + 5), a3v, R5); \
    Z6 = fmaf(W2T(i, JB + 6), a0, Z6);  P6 = fmaf(W2T(i, JB + 6), a1v, P6); \
    Q6 = fmaf(W2T(i, JB + 6), a2v, Q6); R6 = fmaf(W2T(i, JB + 6), a3v, R6); \
    Z7 = fmaf(W2T(i, JB + 7), a0, Z7);  P7 = fmaf(W2T(i, JB + 7), a1v, P7); \
    Q7 = fmaf(W2T(i, JB + 7), a2v, Q7); R7 = fmaf(W2T(i, JB + 7), a3v, R7);

    // pass A: compute tanh, save it; full jet; accumulate j=0..7
#define IA(i)                                                               \
    {                                                                       \
        float t  = fast_tanh(fmaf(CC(i), xr, B1(i)));                       \
        T##i = t;                                                           \
        float t2 = t * t;                                                   \
        float p  = 1.0f - t2;                                               \
        float tp = t * p;                                                   \
        float g  = fmaf(-3.0f, t2, 1.0f);                                   \
        float a1v = p * CC(i);                                              \
        float a2v = tp * K2(i);                                             \
        float a3v = (p * g) * K3(i);                                        \
        ACC8(i, t, a1v, a2v, a3v, 0)                                        \
    }

    // pass B: rebuild jet from saved tanh; accumulate j=8..15
#define IB(i)                                                               \
    {                                                                       \
        float t  = T##i;                                                    \
        float t2 = t * t;                                                   \
        float p  = 1.0f - t2;                                               \
        float tp = t * p;                                                   \
        float g  = fmaf(-3.0f, t2, 1.0f);                                   \
        float a1v = p * CC(i);                                              \
        float a2v = tp * K2(i);                                             \
        float a3v = (p * g) * K3(i);                                        \
        ACC8(i, t, a1v, a2v, a3v, 8)                                        \
    }

#define EPI(j, Zv, Pv, Qv, Rv)                                              \
    {                                                                       \
        float t  = fast_tanh(Zv);                                           \
        float t2 = t * t;                                                   \
        float p  = 1.0f - t2;                                               \
        float tp = t * p;                                                   \
        float g  = fmaf(-3.0f, t2, 1.0f);                                   \
        float zp = Pv, zpp = Qv, zppp = Rv;                                 \
        float zp2 = zp * zp;                                                \
        float a2p   = p * zp;                                               \
        float a2pp  = fmaf(-2.0f * tp, zp2, p * zpp);                       \
        float a2ppp = fmaf(-2.0f * (p * g), zp2 * zp,                       \
                           fmaf(-6.0f * tp, zp * zpp, p * zppp));           \
        u    = fmaf(W30(j), t,     u);                                      \
        up   = fmaf(W30(j), a2p,   up);                                     \
        w    = fmaf(W31(j), t,     w);                                      \
        wp   = fmaf(W31(j), a2p,   wp);                                     \
        wpp  = fmaf(W31(j), a2pp,  wpp);                                    \
        wppp = fmaf(W31(j), a2ppp, wppp);                                   \
    }

    {   // ---- pass A: j = 0..7 ----
        float Z0 = B2(0), Z1 = B2(1), Z2 = B2(2), Z3 = B2(3),
              Z4 = B2(4), Z5 = B2(5), Z6 = B2(6), Z7 = B2(7);
        float P0 = 0, P1 = 0, P2 = 0, P3 = 0, P4 = 0, P5 = 0, P6 = 0, P7 = 0;
        float Q0 = 0, Q1 = 0, Q2 = 0, Q3 = 0, Q4 = 0, Q5 = 0, Q6 = 0, Q7 = 0;
        float R0 = 0, R1 = 0, R2 = 0, R3 = 0, R4 = 0, R5 = 0, R6 = 0, R7 = 0;
        IA(0)  IA(1)  IA(2)  IA(3)  IA(4)  IA(5)  IA(6)  IA(7)
        IA(8)  IA(9)  IA(10) IA(11) IA(12) IA(13) IA(14) IA(15)
        EPI(0, Z0, P0, Q0, R0) EPI(1, Z1, P1, Q1, R1)
        EPI(2, Z2, P2, Q2, R2) EPI(3, Z3, P3, Q3, R3)
        EPI(4, Z4, P4, Q4, R4) EPI(5, Z5, P5, Q5, R5)
        EPI(6, Z6, P6, Q6, R6) EPI(7, Z7, P7, Q7, R7)
    }
    {   // ---- pass B: j = 8..15 ----
        float Z0 = B2(8),  Z1 = B2(9),  Z2 = B2(10), Z3 = B2(11),
              Z4 = B2(12), Z5 = B2(13), Z6 = B2(14), Z7 = B2(15);
        float P0 = 0, P1 = 0, P2 = 0, P3 = 0, P4 = 0, P5 = 0, P6 = 0, P7 = 0;
        float Q0 = 0, Q1 = 0, Q2 = 0, Q3 = 0, Q4 = 0, Q5 = 0, Q6 = 0, Q7 = 0;
        float R0 = 0, R1 = 0, R2 = 0, R3 = 0, R4 = 0, R5 = 0, R6 = 0, R7 = 0;
        IB(0)  IB(1)  IB(2)  IB(3)  IB(4)  IB(5)  IB(6)  IB(7)
        IB(8)  IB(9)  IB(10) IB(11) IB(12) IB(13) IB(14) IB(15)
        EPI(8,  Z0, P0, Q0, R0) EPI(9,  Z1, P1, Q1, R1)
        EPI(10, Z2, P2, Q2, R2) EPI(11, Z3, P3, Q3, R3)
        EPI(12, Z4, P4, Q4, R4) EPI(13, Z5, P5, Q5, R5)
        EPI(14, Z6, P6, Q6, R6) EPI(15, Z7, P7, Q7, R7)
    }

    u += cb[112];
    w += cb[113];

    float Nax = EA_CONST * fmaf(0.5f * wp, wp, up);
    out[idx]         = u;
    out[n + idx]     = w;
    out[2 * n + idx] = wp;
    out[3 * n + idx] = Nax;
    out[4 * n + idx] = -EI_CONST * wpp;
    out[5 * n + idx] = fmaf(Nax, wp, -EI_CONST * wppp);
}

extern "C" void kernel_launch(void* const* d_in, const int* in_sizes, int n_in,
                              void* d_out, int out_size, void* d_ws, size_t ws_size,
                              hipStream_t stream) {
    const float* x  = (const float*)d_in[0];
    const float* W1 = (const float*)d_in[1];
    const float* b1 = (const float*)d_in[2];
    const float* W2 = (const float*)d_in[3];
    const float* b2 = (const float*)d_in[4];
    const float* W3 = (const float*)d_in[5];
    const float* b3 = (const float*)d_in[6];
    float* out = (float*)d_out;
    float* cb  = (float*)d_ws;    // 384 floats

    int n = in_sizes[0];
    pinn_prep<<<1, 256, 0, stream>>>(W1, b1, W2, b2, W3, b3, cb);
    int block = 256;
    int grid = (n + block - 1) / block;
    pinn_main<<<grid, block, 0, stream>>>(x, cb, out, n);
}